// Round 10
// baseline (263.924 us; speedup 1.0000x reference)
//
#include <hip/hip_runtime.h>

#define N_USERS 100000
#define N_ITEMS 50000
#define N_NODES 150000
#define NEDGES  4000000
#define EMB     64
#define BATCH   16384

#define RSHIFT  9
#define RPB     512                          // rows per bucket
#define NBKT    ((N_NODES + RPB - 1) / RPB)  // 293
#define BCAP    24576                        // max edges/bucket

#define PC_BS   1024
#define PC_CH   16384
#define PC_EPT  (PC_CH / PC_BS)                 // 16 edges/thread
#define PC_NWG  ((NEDGES + PC_CH - 1) / PC_CH)  // 245

// ---------------- helpers ----------------

typedef float f32x2 __attribute__((ext_vector_type(2)));

__device__ __forceinline__ unsigned short f2b(float f) {  // fp32 -> bf16 RNE
    unsigned u = __float_as_uint(f);
    return (unsigned short)((u + 0x7FFFu + ((u >> 16) & 1u)) >> 16);
}
__device__ __forceinline__ float b2f_lo(unsigned v) { return __uint_as_float(v << 16); }
__device__ __forceinline__ float b2f_hi(unsigned v) { return __uint_as_float(v & 0xFFFF0000u); }

// accumulate 8 bf16 (uint4) into 4 packed f32x2 accumulators (v_pk_add_f32)
__device__ __forceinline__ void acc8p(f32x2* a, uint4 v) {
    f32x2 p0, p1, p2, p3;
    p0.x = b2f_lo(v.x); p0.y = b2f_hi(v.x);
    p1.x = b2f_lo(v.y); p1.y = b2f_hi(v.y);
    p2.x = b2f_lo(v.z); p2.y = b2f_hi(v.z);
    p3.x = b2f_lo(v.w); p3.y = b2f_hi(v.w);
    a[0] += p0; a[1] += p1; a[2] += p2; a[3] += p3;
}

__device__ __forceinline__ uint4 ldF(const char* __restrict__ Fb, unsigned off) {
    return *(const uint4*)(Fb + off);
}

// gather-accumulate one row's neighborhood [j,end) into A[4] (8-lane, uint4)
__device__ __forceinline__ void gather_row(const char* __restrict__ Fb,
                                           const int* __restrict__ cols,
                                           int j, int end, unsigned lb, f32x2* A) {
    int nscal = (4 - (j & 3)) & 3;   // align to int4
    for (int k = 0; k < nscal && j < end; ++k, ++j)
        acc8p(A, ldF(Fb, ((unsigned)cols[j] << 7) | lb));
    for (; j + 4 <= end; j += 4) {
        int4 c = *(const int4*)(cols + j);
        uint4 v0 = ldF(Fb, ((unsigned)c.x << 7) | lb);
        uint4 v1 = ldF(Fb, ((unsigned)c.y << 7) | lb);
        uint4 v2 = ldF(Fb, ((unsigned)c.z << 7) | lb);
        uint4 v3 = ldF(Fb, ((unsigned)c.w << 7) | lb);
        acc8p(A, v0); acc8p(A, v1); acc8p(A, v2); acc8p(A, v3);
    }
    for (; j < end; ++j)
        acc8p(A, ldF(Fb, ((unsigned)cols[j] << 7) | lb));
}

// ---------------- CSR build ----------------

__global__ void k_zero(int* __restrict__ bcursor) {
    int i = blockIdx.x * blockDim.x + threadIdx.x;
    if (i < NBKT) bcursor[i] = 0;
}

// LDS-staged bucket partition; edges cached in registers across the two passes
__global__ __launch_bounds__(PC_BS) void k_partC(const int* __restrict__ erow,
                                                 const int* __restrict__ ecol,
                                                 int* __restrict__ bcursor,
                                                 unsigned* __restrict__ tmp) {
    __shared__ int cnt[NBKT];
    __shared__ int base_[NBKT];
    const int t = threadIdx.x;
    for (int i = t; i < NBKT; i += PC_BS) cnt[i] = 0;
    __syncthreads();
    const int e0 = blockIdx.x * PC_CH;
    int rr[PC_EPT], cc[PC_EPT];
#pragma unroll
    for (int k = 0; k < PC_EPT; ++k) {
        int e = e0 + t + k * PC_BS;
        if (e < NEDGES) {
            rr[k] = erow[e];
            cc[k] = ecol[e];
            atomicAdd(&cnt[rr[k] >> RSHIFT], 1);
        } else rr[k] = -1;
    }
    __syncthreads();
    for (int i = t; i < NBKT; i += PC_BS) {
        base_[i] = cnt[i] ? atomicAdd(&bcursor[i], cnt[i]) : 0;
        cnt[i] = 0;
    }
    __syncthreads();
#pragma unroll
    for (int k = 0; k < PC_EPT; ++k) {
        if (rr[k] >= 0) {
            int b = rr[k] >> RSHIFT;
            int pos = base_[b] + atomicAdd(&cnt[b], 1);
            if (pos < BCAP)
                tmp[(size_t)b * BCAP + pos] =
                    ((unsigned)(rr[k] & (RPB - 1)) << 18) | (unsigned)cc[k];
        }
    }
}

// scan of per-bucket totals
__global__ __launch_bounds__(512) void k_bscan(const int* __restrict__ bcursor,
                                               int* __restrict__ bbase,
                                               int* __restrict__ rowptr) {
    __shared__ int s[512];
    const int t = threadIdx.x;
    int v = 0;
    if (t < NBKT) { v = bcursor[t]; if (v > BCAP) v = BCAP; }
    s[t] = v;
    __syncthreads();
    for (int off = 1; off < 512; off <<= 1) {
        int u = (t >= off) ? s[t - off] : 0;
        __syncthreads();
        s[t] += u;
        __syncthreads();
    }
    if (t < NBKT) bbase[t] = s[t] - v;  // exclusive
    if (t == 511) { bbase[NBKT] = s[511]; rowptr[N_NODES] = s[511]; }
}

// fused: row count (LDS) -> LDS scan -> rowptr + dinv/s2/srt -> place edges
__global__ __launch_bounds__(512) void k_rows_place(const unsigned* __restrict__ tmp,
                                                    const int* __restrict__ bcursor,
                                                    const int* __restrict__ bbase,
                                                    int* __restrict__ rowptr,
                                                    float* __restrict__ dinv,
                                                    float* __restrict__ s2,
                                                    float* __restrict__ srt,
                                                    int* __restrict__ csrc) {
    __shared__ int rc[RPB];
    __shared__ int pre[RPB];
    const int b = blockIdx.x;
    const int t = threadIdx.x;
    rc[t] = 0;
    __syncthreads();
    int n = bcursor[b]; if (n > BCAP) n = BCAP;
    const unsigned* tp = tmp + (size_t)b * BCAP;
    for (int i = t; i < n; i += 512) atomicAdd(&rc[tp[i] >> 18], 1);
    __syncthreads();
    int my = rc[t];
    pre[t] = my;
    __syncthreads();
    for (int off = 1; off < 512; off <<= 1) {
        int u = (t >= off) ? pre[t - off] : 0;
        __syncthreads();
        pre[t] += u;
        __syncthreads();
    }
    int ex   = pre[t] - my;
    int base = bbase[b];
    int r = b * RPB + t;
    if (r < N_NODES) {
        float sr = sqrtf((float)my) + 1e-6f;   // 1/dinv
        float dv = 1.0f / sr;
        rowptr[r] = base + ex;
        dinv[r] = dv;
        s2[r]   = dv * dv;
        srt[r]  = sr;
    }
    __syncthreads();
    rc[t] = base + ex;               // absolute write cursor per row
    __syncthreads();
    for (int i = t; i < n; i += 512) {
        unsigned pk = tp[i];
        int slot = atomicAdd(&rc[pk >> 18], 1);
        csrc[slot] = (int)(pk & 0x3FFFFu);
    }
}

// F0 = dinv * E0, bf16
__global__ void k_cast(const float* __restrict__ E0, const float* __restrict__ dinv,
                       unsigned short* __restrict__ F0) {
    int i = blockIdx.x * blockDim.x + threadIdx.x;  // one float4 per thread
    const int total = N_NODES * EMB / 4;
    if (i >= total) return;
    float dv = dinv[i >> 4];
    float4 v = ((const float4*)E0)[i];
    ushort4 o;
    o.x = f2b(dv * v.x); o.y = f2b(dv * v.y);
    o.z = f2b(dv * v.z); o.w = f2b(dv * v.w);
    ((ushort4*)F0)[i] = o;
}

// ---------------- dense SpMM: TWO adjacent rows per 8-lane group ------------
// Interleaved edge streams double the loads in flight per wave (MLP).

__global__ __launch_bounds__(256) void k_spmm2(const unsigned short* __restrict__ Fin,
                                               unsigned short* __restrict__ Fout,
                                               const int* __restrict__ rowptr,
                                               const int* __restrict__ cols,
                                               const float* __restrict__ s2) {
    int pair = (blockIdx.x * blockDim.x + threadIdx.x) >> 3;
    int lane = threadIdx.x & 7;
    int g0 = pair * 2;
    if (g0 >= N_NODES) return;          // N_NODES even -> g1 always valid
    int g1 = g0 + 1;
    const char* Fb = (const char*)Fin;
    const unsigned lb = (unsigned)lane << 4;

    int j0 = rowptr[g0], e0 = rowptr[g0 + 1];
    int j1 = e0,          e1 = rowptr[g1 + 1];   // rowptr[g1] == e0

    f32x2 A0[4], A1[4];
#pragma unroll
    for (int k = 0; k < 4; ++k) { A0[k] = (f32x2)0.0f; A1[k] = (f32x2)0.0f; }

    // alignment prologues (scalar)
    {
        int ns = (4 - (j0 & 3)) & 3;
        for (int k = 0; k < ns && j0 < e0; ++k, ++j0)
            acc8p(A0, ldF(Fb, ((unsigned)cols[j0] << 7) | lb));
        ns = (4 - (j1 & 3)) & 3;
        for (int k = 0; k < ns && j1 < e1; ++k, ++j1)
            acc8p(A1, ldF(Fb, ((unsigned)cols[j1] << 7) | lb));
    }
    // interleaved main loop: 8 independent gathers in flight
    for (; j0 + 4 <= e0 && j1 + 4 <= e1; j0 += 4, j1 += 4) {
        int4 c0 = *(const int4*)(cols + j0);
        int4 c1 = *(const int4*)(cols + j1);
        uint4 v0 = ldF(Fb, ((unsigned)c0.x << 7) | lb);
        uint4 v1 = ldF(Fb, ((unsigned)c1.x << 7) | lb);
        uint4 v2 = ldF(Fb, ((unsigned)c0.y << 7) | lb);
        uint4 v3 = ldF(Fb, ((unsigned)c1.y << 7) | lb);
        uint4 v4 = ldF(Fb, ((unsigned)c0.z << 7) | lb);
        uint4 v5 = ldF(Fb, ((unsigned)c1.z << 7) | lb);
        uint4 v6 = ldF(Fb, ((unsigned)c0.w << 7) | lb);
        uint4 v7 = ldF(Fb, ((unsigned)c1.w << 7) | lb);
        acc8p(A0, v0); acc8p(A1, v1); acc8p(A0, v2); acc8p(A1, v3);
        acc8p(A0, v4); acc8p(A1, v5); acc8p(A0, v6); acc8p(A1, v7);
    }
    // drains
    for (; j0 + 4 <= e0; j0 += 4) {
        int4 c = *(const int4*)(cols + j0);
        uint4 v0 = ldF(Fb, ((unsigned)c.x << 7) | lb);
        uint4 v1 = ldF(Fb, ((unsigned)c.y << 7) | lb);
        uint4 v2 = ldF(Fb, ((unsigned)c.z << 7) | lb);
        uint4 v3 = ldF(Fb, ((unsigned)c.w << 7) | lb);
        acc8p(A0, v0); acc8p(A0, v1); acc8p(A0, v2); acc8p(A0, v3);
    }
    for (; j0 < e0; ++j0) acc8p(A0, ldF(Fb, ((unsigned)cols[j0] << 7) | lb));
    for (; j1 + 4 <= e1; j1 += 4) {
        int4 c = *(const int4*)(cols + j1);
        uint4 v0 = ldF(Fb, ((unsigned)c.x << 7) | lb);
        uint4 v1 = ldF(Fb, ((unsigned)c.y << 7) | lb);
        uint4 v2 = ldF(Fb, ((unsigned)c.z << 7) | lb);
        uint4 v3 = ldF(Fb, ((unsigned)c.w << 7) | lb);
        acc8p(A1, v0); acc8p(A1, v1); acc8p(A1, v2); acc8p(A1, v3);
    }
    for (; j1 < e1; ++j1) acc8p(A1, ldF(Fb, ((unsigned)cols[j1] << 7) | lb));

    float sA = s2[g0], sB = s2[g1];
    unsigned o0 = ((unsigned)f2b(sA * A0[0].y) << 16) | f2b(sA * A0[0].x);
    unsigned o1 = ((unsigned)f2b(sA * A0[1].y) << 16) | f2b(sA * A0[1].x);
    unsigned o2 = ((unsigned)f2b(sA * A0[2].y) << 16) | f2b(sA * A0[2].x);
    unsigned o3 = ((unsigned)f2b(sA * A0[3].y) << 16) | f2b(sA * A0[3].x);
    *(uint4*)((char*)Fout + (((unsigned)g0 << 7) | lb)) = make_uint4(o0, o1, o2, o3);
    o0 = ((unsigned)f2b(sB * A1[0].y) << 16) | f2b(sB * A1[0].x);
    o1 = ((unsigned)f2b(sB * A1[1].y) << 16) | f2b(sB * A1[1].x);
    o2 = ((unsigned)f2b(sB * A1[2].y) << 16) | f2b(sB * A1[2].x);
    o3 = ((unsigned)f2b(sB * A1[3].y) << 16) | f2b(sB * A1[3].x);
    *(uint4*)((char*)Fout + (((unsigned)g1 << 7) | lb)) = make_uint4(o0, o1, o2, o3);
}

// ---------------- fused tail: hop-3 (batch rows) + E-sum + dot --------------
// 16 lanes per query: lanes 0-7 user side, 8-15 item side, 8 comps/lane.

__global__ __launch_bounds__(256) void k_tail(const float* __restrict__ E0,
                                              const unsigned short* __restrict__ F1,
                                              const unsigned short* __restrict__ F2,
                                              const int* __restrict__ rowptr,
                                              const int* __restrict__ cols,
                                              const float* __restrict__ s2,
                                              const float* __restrict__ srt,
                                              const int* __restrict__ ub,
                                              const int* __restrict__ ib,
                                              float* __restrict__ out) {
    int q      = (blockIdx.x * blockDim.x + threadIdx.x) >> 4;
    int lane16 = threadIdx.x & 15;
    int side   = lane16 >> 3;
    int lane8  = lane16 & 7;
    if (q >= BATCH) return;
    int g = side ? (N_USERS + ib[q]) : ub[q];
    const unsigned lb = (unsigned)lane8 << 4;

    // hop 3 for this row: A = sum_{c in N(g)} F2[c]
    f32x2 A[4];
#pragma unroll
    for (int k = 0; k < 4; ++k) A[k] = (f32x2)0.0f;
    gather_row((const char*)F2, cols, rowptr[g], rowptr[g + 1], lb, A);

    float s2g = s2[g], sr = srt[g];
    f32x2 sr2; sr2.x = sr; sr2.y = sr;
    f32x2 s32; s32.x = s2g * sr; s32.y = s2g * sr;  // srt*s2 for F3 term

    // side sum: E0[g] + sr*F1[g] + sr*F2[g] + sr*(s2*A)
    const float* e0p = E0 + (size_t)g * EMB + lane8 * 8;
    float4 ea = *(const float4*)e0p;
    float4 eb = *(const float4*)(e0p + 4);
    f32x2 S[4];
    S[0].x = ea.x; S[0].y = ea.y; S[1].x = ea.z; S[1].y = ea.w;
    S[2].x = eb.x; S[2].y = eb.y; S[3].x = eb.z; S[3].y = eb.w;
    uint4 v1 = ldF((const char*)F1, ((unsigned)g << 7) | lb);
    uint4 v2 = ldF((const char*)F2, ((unsigned)g << 7) | lb);
    f32x2 t;
#define ADDV(vv, kk, lo, hi) \
    t.x = b2f_lo(lo); t.y = b2f_hi(hi); S[kk] += sr2 * t;
    ADDV(v1, 0, v1.x, v1.x) ADDV(v1, 1, v1.y, v1.y)
    ADDV(v1, 2, v1.z, v1.z) ADDV(v1, 3, v1.w, v1.w)
    ADDV(v2, 0, v2.x, v2.x) ADDV(v2, 1, v2.y, v2.y)
    ADDV(v2, 2, v2.z, v2.z) ADDV(v2, 3, v2.w, v2.w)
#undef ADDV
#pragma unroll
    for (int k = 0; k < 4; ++k) S[k] += s32 * A[k];

    // cross-octet dot: lane l (user) x lane l^8 (item)
    float p = 0.0f;
#pragma unroll
    for (int k = 0; k < 4; ++k) {
        p += S[k].x * __shfl_xor(S[k].x, 8);
        p += S[k].y * __shfl_xor(S[k].y, 8);
    }
    p += __shfl_xor(p, 1);
    p += __shfl_xor(p, 2);
    p += __shfl_xor(p, 4);
    if (lane16 == 0) out[q] = p * (1.0f / 16.0f);  // 1/(K+1)^2
}

// ---------------- launch ----------------

static inline char* align16(char* p) {
    return (char*)(((uintptr_t)p + 15) & ~(uintptr_t)15);
}

extern "C" void kernel_launch(void* const* d_in, const int* in_sizes, int n_in,
                              void* d_out, int out_size, void* d_ws, size_t ws_size,
                              hipStream_t stream) {
    const float* E0   = (const float*)d_in[0];
    const int*   erow = (const int*)d_in[2];
    const int*   ecol = (const int*)d_in[3];
    const int*   ub   = (const int*)d_in[4];
    const int*   ib   = (const int*)d_in[5];
    float* pred = (float*)d_out;

    char* p = (char*)d_ws;
    unsigned short* F0  = (unsigned short*)p; p = align16(p + (size_t)N_NODES * EMB * 2);
    unsigned short* Abf = (unsigned short*)p; p = align16(p + (size_t)N_NODES * EMB * 2);
    unsigned short* Bbf = (unsigned short*)p; p = align16(p + (size_t)N_NODES * EMB * 2);
    int*   bcursor = (int*)p;      p = align16(p + (size_t)NBKT * 4);
    int*   bbase   = (int*)p;      p = align16(p + (size_t)(NBKT + 1) * 4);
    int*   rowptr  = (int*)p;      p = align16(p + (size_t)(N_NODES + 1) * 4);
    float* dinv    = (float*)p;    p = align16(p + (size_t)N_NODES * 4);
    float* s2      = (float*)p;    p = align16(p + (size_t)N_NODES * 4);
    float* srt     = (float*)p;    p = align16(p + (size_t)N_NODES * 4);
    int*   csrc    = (int*)p;      p = align16(p + (size_t)NEDGES * 4);
    unsigned* tmp  = (unsigned*)p; p = align16(p + (size_t)NBKT * BCAP * 4);

    const int BS = 256;
    // CSR build
    k_zero<<<(NBKT + BS - 1) / BS, BS, 0, stream>>>(bcursor);
    k_partC<<<PC_NWG, PC_BS, 0, stream>>>(erow, ecol, bcursor, tmp);
    k_bscan<<<1, 512, 0, stream>>>(bcursor, bbase, rowptr);
    k_rows_place<<<NBKT, 512, 0, stream>>>(tmp, bcursor, bbase, rowptr, dinv, s2, srt, csrc);
    k_cast<<<(N_NODES * EMB / 4 + BS - 1) / BS, BS, 0, stream>>>(E0, dinv, F0);

    const int spmm2_grid = ((N_NODES / 2) * 8 + BS - 1) / BS;

    // hop 1: F0 -> Abf (dense, paired rows)
    k_spmm2<<<spmm2_grid, BS, 0, stream>>>(F0, Abf, rowptr, csrc, s2);
    // hop 2: Abf -> Bbf (dense, paired rows)
    k_spmm2<<<spmm2_grid, BS, 0, stream>>>(Abf, Bbf, rowptr, csrc, s2);
    // fused hop-3 + E-sum + dot
    k_tail<<<(BATCH * 16 + BS - 1) / BS, BS, 0, stream>>>(E0, Abf, Bbf, rowptr, csrc,
                                                          s2, srt, ub, ib, pred);
}

// Round 11
// 228.736 us; speedup vs baseline: 1.1538x; 1.1538x over previous
//
#include <hip/hip_runtime.h>

#define N_USERS 100000
#define N_ITEMS 50000
#define N_NODES 150000
#define NEDGES  4000000
#define EMB     64
#define BATCH   16384

#define RSHIFT  9
#define RPB     512                          // rows per bucket
#define NBKT    ((N_NODES + RPB - 1) / RPB)  // 293
#define BCAP    24576                        // max edges/bucket

#define PC_BS   1024
#define PC_CH   16384
#define PC_EPT  (PC_CH / PC_BS)                 // 16 edges/thread
#define PC_NWG  ((NEDGES + PC_CH - 1) / PC_CH)  // 245

// ---------------- helpers ----------------

typedef float f32x2 __attribute__((ext_vector_type(2)));

__device__ __forceinline__ unsigned short f2b(float f) {  // fp32 -> bf16 RNE
    unsigned u = __float_as_uint(f);
    return (unsigned short)((u + 0x7FFFu + ((u >> 16) & 1u)) >> 16);
}
__device__ __forceinline__ float b2f_lo(unsigned v) { return __uint_as_float(v << 16); }
__device__ __forceinline__ float b2f_hi(unsigned v) { return __uint_as_float(v & 0xFFFF0000u); }

// accumulate 8 bf16 (uint4) into 4 packed f32x2 accumulators (v_pk_add_f32)
__device__ __forceinline__ void acc8p(f32x2* a, uint4 v) {
    f32x2 p0, p1, p2, p3;
    p0.x = b2f_lo(v.x); p0.y = b2f_hi(v.x);
    p1.x = b2f_lo(v.y); p1.y = b2f_hi(v.y);
    p2.x = b2f_lo(v.z); p2.y = b2f_hi(v.z);
    p3.x = b2f_lo(v.w); p3.y = b2f_hi(v.w);
    a[0] += p0; a[1] += p1; a[2] += p2; a[3] += p3;
}

__device__ __forceinline__ uint4 ldF(const char* __restrict__ Fb, unsigned off) {
    return *(const uint4*)(Fb + off);
}

// gather-accumulate one row's neighborhood [j,end) into A[4] (8-lane, uint4)
__device__ __forceinline__ void gather_row(const char* __restrict__ Fb,
                                           const int* __restrict__ cols,
                                           int j, int end, unsigned lb, f32x2* A,
                                           f32x2* B) {
    int nscal = (4 - (j & 3)) & 3;   // align to int4
    for (int k = 0; k < nscal && j < end; ++k, ++j)
        acc8p(A, ldF(Fb, ((unsigned)cols[j] << 7) | lb));
    for (; j + 8 <= end; j += 8) {
        int4 c0 = *(const int4*)(cols + j);
        int4 c1 = *(const int4*)(cols + j + 4);
        uint4 v0 = ldF(Fb, ((unsigned)c0.x << 7) | lb);
        uint4 v1 = ldF(Fb, ((unsigned)c0.y << 7) | lb);
        uint4 v2 = ldF(Fb, ((unsigned)c0.z << 7) | lb);
        uint4 v3 = ldF(Fb, ((unsigned)c0.w << 7) | lb);
        uint4 v4 = ldF(Fb, ((unsigned)c1.x << 7) | lb);
        uint4 v5 = ldF(Fb, ((unsigned)c1.y << 7) | lb);
        uint4 v6 = ldF(Fb, ((unsigned)c1.z << 7) | lb);
        uint4 v7 = ldF(Fb, ((unsigned)c1.w << 7) | lb);
        acc8p(A, v0); acc8p(B, v1); acc8p(A, v2); acc8p(B, v3);
        acc8p(A, v4); acc8p(B, v5); acc8p(A, v6); acc8p(B, v7);
    }
    for (; j + 4 <= end; j += 4) {
        int4 c = *(const int4*)(cols + j);
        uint4 v0 = ldF(Fb, ((unsigned)c.x << 7) | lb);
        uint4 v1 = ldF(Fb, ((unsigned)c.y << 7) | lb);
        uint4 v2 = ldF(Fb, ((unsigned)c.z << 7) | lb);
        uint4 v3 = ldF(Fb, ((unsigned)c.w << 7) | lb);
        acc8p(A, v0); acc8p(B, v1); acc8p(A, v2); acc8p(B, v3);
    }
    for (; j < end; ++j)
        acc8p(A, ldF(Fb, ((unsigned)cols[j] << 7) | lb));
}

// ---------------- CSR build ----------------

__global__ void k_zero(int* __restrict__ bcursor) {
    int i = blockIdx.x * blockDim.x + threadIdx.x;
    if (i < NBKT) bcursor[i] = 0;
}

// LDS-staged bucket partition; edges cached in registers across the two passes
__global__ __launch_bounds__(PC_BS) void k_partC(const int* __restrict__ erow,
                                                 const int* __restrict__ ecol,
                                                 int* __restrict__ bcursor,
                                                 unsigned* __restrict__ tmp) {
    __shared__ int cnt[NBKT];
    __shared__ int base_[NBKT];
    const int t = threadIdx.x;
    for (int i = t; i < NBKT; i += PC_BS) cnt[i] = 0;
    __syncthreads();
    const int e0 = blockIdx.x * PC_CH;
    int rr[PC_EPT], cc[PC_EPT];
#pragma unroll
    for (int k = 0; k < PC_EPT; ++k) {
        int e = e0 + t + k * PC_BS;
        if (e < NEDGES) {
            rr[k] = erow[e];
            cc[k] = ecol[e];
            atomicAdd(&cnt[rr[k] >> RSHIFT], 1);
        } else rr[k] = -1;
    }
    __syncthreads();
    for (int i = t; i < NBKT; i += PC_BS) {
        base_[i] = cnt[i] ? atomicAdd(&bcursor[i], cnt[i]) : 0;
        cnt[i] = 0;
    }
    __syncthreads();
#pragma unroll
    for (int k = 0; k < PC_EPT; ++k) {
        if (rr[k] >= 0) {
            int b = rr[k] >> RSHIFT;
            int pos = base_[b] + atomicAdd(&cnt[b], 1);
            if (pos < BCAP)
                tmp[(size_t)b * BCAP + pos] =
                    ((unsigned)(rr[k] & (RPB - 1)) << 18) | (unsigned)cc[k];
        }
    }
}

// scan of per-bucket totals
__global__ __launch_bounds__(512) void k_bscan(const int* __restrict__ bcursor,
                                               int* __restrict__ bbase,
                                               int* __restrict__ rowptr) {
    __shared__ int s[512];
    const int t = threadIdx.x;
    int v = 0;
    if (t < NBKT) { v = bcursor[t]; if (v > BCAP) v = BCAP; }
    s[t] = v;
    __syncthreads();
    for (int off = 1; off < 512; off <<= 1) {
        int u = (t >= off) ? s[t - off] : 0;
        __syncthreads();
        s[t] += u;
        __syncthreads();
    }
    if (t < NBKT) bbase[t] = s[t] - v;  // exclusive
    if (t == 511) { bbase[NBKT] = s[511]; rowptr[N_NODES] = s[511]; }
}

// fused: row count (LDS) -> LDS scan -> rowptr + dinv/s2/srt -> place edges
__global__ __launch_bounds__(512) void k_rows_place(const unsigned* __restrict__ tmp,
                                                    const int* __restrict__ bcursor,
                                                    const int* __restrict__ bbase,
                                                    int* __restrict__ rowptr,
                                                    float* __restrict__ dinv,
                                                    float* __restrict__ s2,
                                                    float* __restrict__ srt,
                                                    int* __restrict__ csrc) {
    __shared__ int rc[RPB];
    __shared__ int pre[RPB];
    const int b = blockIdx.x;
    const int t = threadIdx.x;
    rc[t] = 0;
    __syncthreads();
    int n = bcursor[b]; if (n > BCAP) n = BCAP;
    const unsigned* tp = tmp + (size_t)b * BCAP;
    for (int i = t; i < n; i += 512) atomicAdd(&rc[tp[i] >> 18], 1);
    __syncthreads();
    int my = rc[t];
    pre[t] = my;
    __syncthreads();
    for (int off = 1; off < 512; off <<= 1) {
        int u = (t >= off) ? pre[t - off] : 0;
        __syncthreads();
        pre[t] += u;
        __syncthreads();
    }
    int ex   = pre[t] - my;
    int base = bbase[b];
    int r = b * RPB + t;
    if (r < N_NODES) {
        float sr = sqrtf((float)my) + 1e-6f;   // 1/dinv
        float dv = 1.0f / sr;
        rowptr[r] = base + ex;
        dinv[r] = dv;
        s2[r]   = dv * dv;
        srt[r]  = sr;
    }
    __syncthreads();
    rc[t] = base + ex;               // absolute write cursor per row
    __syncthreads();
    for (int i = t; i < n; i += 512) {
        unsigned pk = tp[i];
        int slot = atomicAdd(&rc[pk >> 18], 1);
        csrc[slot] = (int)(pk & 0x3FFFFu);
    }
}

// F0 = dinv * E0, bf16
__global__ void k_cast(const float* __restrict__ E0, const float* __restrict__ dinv,
                       unsigned short* __restrict__ F0) {
    int i = blockIdx.x * blockDim.x + threadIdx.x;  // one float4 per thread
    const int total = N_NODES * EMB / 4;
    if (i >= total) return;
    float dv = dinv[i >> 4];
    float4 v = ((const float4*)E0)[i];
    ushort4 o;
    o.x = f2b(dv * v.x); o.y = f2b(dv * v.y);
    o.z = f2b(dv * v.z); o.w = f2b(dv * v.w);
    ((ushort4*)F0)[i] = o;
}

// ---------------- dense SpMM: one row per 8-lane group (proven form) --------

__device__ __forceinline__ void spmm_row_st(const unsigned short* __restrict__ Fin,
                                            unsigned short* __restrict__ Fout,
                                            const int* __restrict__ cols,
                                            int beg, int end, int g, int lane, float s) {
    const char* Fb = (const char*)Fin;
    const unsigned lb = (unsigned)lane << 4;
    f32x2 A[4], B[4];
#pragma unroll
    for (int k = 0; k < 4; ++k) { A[k] = (f32x2)0.0f; B[k] = (f32x2)0.0f; }
    gather_row(Fb, cols, beg, end, lb, A, B);
#pragma unroll
    for (int k = 0; k < 4; ++k) A[k] += B[k];
    unsigned o0 = ((unsigned)f2b(s * A[0].y) << 16) | f2b(s * A[0].x);
    unsigned o1 = ((unsigned)f2b(s * A[1].y) << 16) | f2b(s * A[1].x);
    unsigned o2 = ((unsigned)f2b(s * A[2].y) << 16) | f2b(s * A[2].x);
    unsigned o3 = ((unsigned)f2b(s * A[3].y) << 16) | f2b(s * A[3].x);
    *(uint4*)((char*)Fout + (((unsigned)g << 7) | lb)) = make_uint4(o0, o1, o2, o3);
}

__global__ __launch_bounds__(256) void k_spmm(const unsigned short* __restrict__ Fin,
                                              unsigned short* __restrict__ Fout,
                                              const int* __restrict__ rowptr,
                                              const int* __restrict__ cols,
                                              const float* __restrict__ s2) {
    int g    = (blockIdx.x * blockDim.x + threadIdx.x) >> 3;
    int lane = threadIdx.x & 7;
    if (g >= N_NODES) return;
    spmm_row_st(Fin, Fout, cols, rowptr[g], rowptr[g + 1], g, lane, s2[g]);
}

// ---------------- fused tail: hop-3 (batch rows) + E-sum + dot --------------
// 16 lanes per query: lanes 0-7 user side, 8-15 item side, 8 comps/lane.

__global__ __launch_bounds__(256) void k_tail(const float* __restrict__ E0,
                                              const unsigned short* __restrict__ F1,
                                              const unsigned short* __restrict__ F2,
                                              const int* __restrict__ rowptr,
                                              const int* __restrict__ cols,
                                              const float* __restrict__ s2,
                                              const float* __restrict__ srt,
                                              const int* __restrict__ ub,
                                              const int* __restrict__ ib,
                                              float* __restrict__ out) {
    int q      = (blockIdx.x * blockDim.x + threadIdx.x) >> 4;
    int lane16 = threadIdx.x & 15;
    int side   = lane16 >> 3;
    int lane8  = lane16 & 7;
    if (q >= BATCH) return;
    int g = side ? (N_USERS + ib[q]) : ub[q];
    const unsigned lb = (unsigned)lane8 << 4;

    // hop 3 for this row: A = sum_{c in N(g)} F2[c]
    f32x2 A[4], B[4];
#pragma unroll
    for (int k = 0; k < 4; ++k) { A[k] = (f32x2)0.0f; B[k] = (f32x2)0.0f; }
    gather_row((const char*)F2, cols, rowptr[g], rowptr[g + 1], lb, A, B);
#pragma unroll
    for (int k = 0; k < 4; ++k) A[k] += B[k];

    float s2g = s2[g], sr = srt[g];
    f32x2 sr2; sr2.x = sr; sr2.y = sr;
    f32x2 s32; s32.x = s2g * sr; s32.y = s2g * sr;  // srt*s2 for F3 term

    // side sum: E0[g] + sr*F1[g] + sr*F2[g] + sr*(s2*A)
    const float* e0p = E0 + (size_t)g * EMB + lane8 * 8;
    float4 ea = *(const float4*)e0p;
    float4 eb = *(const float4*)(e0p + 4);
    f32x2 S[4];
    S[0].x = ea.x; S[0].y = ea.y; S[1].x = ea.z; S[1].y = ea.w;
    S[2].x = eb.x; S[2].y = eb.y; S[3].x = eb.z; S[3].y = eb.w;
    uint4 v1 = ldF((const char*)F1, ((unsigned)g << 7) | lb);
    uint4 v2 = ldF((const char*)F2, ((unsigned)g << 7) | lb);
    f32x2 t;
#define ADDV(w, kk) \
    t.x = b2f_lo(w); t.y = b2f_hi(w); S[kk] += sr2 * t;
    ADDV(v1.x, 0) ADDV(v1.y, 1) ADDV(v1.z, 2) ADDV(v1.w, 3)
    ADDV(v2.x, 0) ADDV(v2.y, 1) ADDV(v2.z, 2) ADDV(v2.w, 3)
#undef ADDV
#pragma unroll
    for (int k = 0; k < 4; ++k) S[k] += s32 * A[k];

    // cross-octet dot: lane l (user) x lane l^8 (item)
    float p = 0.0f;
#pragma unroll
    for (int k = 0; k < 4; ++k) {
        p += S[k].x * __shfl_xor(S[k].x, 8);
        p += S[k].y * __shfl_xor(S[k].y, 8);
    }
    p += __shfl_xor(p, 1);
    p += __shfl_xor(p, 2);
    p += __shfl_xor(p, 4);
    if (lane16 == 0) out[q] = p * (1.0f / 16.0f);  // 1/(K+1)^2
}

// ---------------- launch ----------------

static inline char* align16(char* p) {
    return (char*)(((uintptr_t)p + 15) & ~(uintptr_t)15);
}

extern "C" void kernel_launch(void* const* d_in, const int* in_sizes, int n_in,
                              void* d_out, int out_size, void* d_ws, size_t ws_size,
                              hipStream_t stream) {
    const float* E0   = (const float*)d_in[0];
    const int*   erow = (const int*)d_in[2];
    const int*   ecol = (const int*)d_in[3];
    const int*   ub   = (const int*)d_in[4];
    const int*   ib   = (const int*)d_in[5];
    float* pred = (float*)d_out;

    char* p = (char*)d_ws;
    unsigned short* F0  = (unsigned short*)p; p = align16(p + (size_t)N_NODES * EMB * 2);
    unsigned short* Abf = (unsigned short*)p; p = align16(p + (size_t)N_NODES * EMB * 2);
    unsigned short* Bbf = (unsigned short*)p; p = align16(p + (size_t)N_NODES * EMB * 2);
    int*   bcursor = (int*)p;      p = align16(p + (size_t)NBKT * 4);
    int*   bbase   = (int*)p;      p = align16(p + (size_t)(NBKT + 1) * 4);
    int*   rowptr  = (int*)p;      p = align16(p + (size_t)(N_NODES + 1) * 4);
    float* dinv    = (float*)p;    p = align16(p + (size_t)N_NODES * 4);
    float* s2      = (float*)p;    p = align16(p + (size_t)N_NODES * 4);
    float* srt     = (float*)p;    p = align16(p + (size_t)N_NODES * 4);
    int*   csrc    = (int*)p;      p = align16(p + (size_t)NEDGES * 4);
    unsigned* tmp  = (unsigned*)p; p = align16(p + (size_t)NBKT * BCAP * 4);

    const int BS = 256;
    // CSR build
    k_zero<<<(NBKT + BS - 1) / BS, BS, 0, stream>>>(bcursor);
    k_partC<<<PC_NWG, PC_BS, 0, stream>>>(erow, ecol, bcursor, tmp);
    k_bscan<<<1, 512, 0, stream>>>(bcursor, bbase, rowptr);
    k_rows_place<<<NBKT, 512, 0, stream>>>(tmp, bcursor, bbase, rowptr, dinv, s2, srt, csrc);
    k_cast<<<(N_NODES * EMB / 4 + BS - 1) / BS, BS, 0, stream>>>(E0, dinv, F0);

    const int spmm_grid = (N_NODES * 8 + BS - 1) / BS;

    // hop 1: F0 -> Abf (dense)
    k_spmm<<<spmm_grid, BS, 0, stream>>>(F0, Abf, rowptr, csrc, s2);
    // hop 2: Abf -> Bbf (dense)
    k_spmm<<<spmm_grid, BS, 0, stream>>>(Abf, Bbf, rowptr, csrc, s2);
    // fused hop-3 + E-sum + dot
    k_tail<<<(BATCH * 16 + BS - 1) / BS, BS, 0, stream>>>(E0, Abf, Bbf, rowptr, csrc,
                                                          s2, srt, ub, ib, pred);
}